// Round 26
// baseline (1171.812 us; speedup 1.0000x reference)
//
#include <hip/hip_runtime.h>
#include <hip/hip_bf16.h>

typedef __hip_bfloat16 bft;
typedef __attribute__((ext_vector_type(8))) short bf16x8;
typedef __attribute__((ext_vector_type(4))) float f32x4;
typedef __attribute__((ext_vector_type(4))) unsigned int u32x4;

#define BLK 256
static constexpr int Cc = 192;     // channels
static constexpr int L  = 192;     // H = W
static constexpr int S  = 36864;   // L*L
static constexpr int Bn = 2;       // batch
static constexpr int HID = 510;    // int(192*2.66)
static constexpr int CH2 = 96;     // FFN chunk height (image rows)
static constexpr int FTR2 = (CH2 + 2) * L;   // 18816 fT rows (with halo)
static constexpr int GTR2 = CH2 * L;         // 18432 gT rows
static constexpr int DWS = 225;    // dwconv LDS row stride (== 1 mod 32)
static constexpr double PI_D = 3.141592653589793238462643383279502884;

__device__ __forceinline__ float ldf(const float* p) { return *p; }
__device__ __forceinline__ float ldf(const bft* p)   { return __bfloat162float(*p); }
__device__ __forceinline__ void  stf(float* p, float v) { *p = v; }
__device__ __forceinline__ void  stf(bft* p, float v)   { *p = __float2bfloat16(v); }
__device__ __forceinline__ unsigned short f2bfu(float f) {
    bft h = __float2bfloat16(f);
    return *reinterpret_cast<const unsigned short*>(&h);
}
__device__ __forceinline__ unsigned short bfu(const bft* p) {
    return *reinterpret_cast<const unsigned short*>(p);
}
__device__ __forceinline__ float bu2f(unsigned short u) {
    unsigned int x = (unsigned int)u << 16;
    return __uint_as_float(x);
}
__device__ __forceinline__ bf16x8 ld8(const unsigned short* p) {   // 4B-aligned
    union { unsigned int u[4]; bf16x8 v; } t;
    const unsigned int* q = reinterpret_cast<const unsigned int*>(p);
    t.u[0] = q[0]; t.u[1] = q[1]; t.u[2] = q[2]; t.u[3] = q[3];
    return t.v;
}
// non-temporal 16B store (streams past L2; outputs here never L2-fit)
__device__ __forceinline__ void nt16(void* p, const void* v) {
    __builtin_nontemporal_store(*reinterpret_cast<const u32x4*>(v),
                                reinterpret_cast<u32x4*>(p));
}
__device__ __forceinline__ void ntf(float* p, float v) {
    __builtin_nontemporal_store(v, p);
}

// ---------------- DCT matrix init -> bf16 direct + transposed ----------------
__global__ __launch_bounds__(BLK) void k_dct_init(bft* __restrict__ dctb,
                                                  bft* __restrict__ dctTb) {
    int idx = blockIdx.x * BLK + threadIdx.x;
    if (idx >= L * L) return;
    int p = idx / L, h = idx - p * L;
    double v = (p == 0) ? sqrt(1.0 / L)
                        : cos(PI_D * p * (2 * h + 1) / (2.0 * L)) * sqrt(2.0 / L);
    bft bv = __float2bfloat16((float)v);
    dctb[p * L + h] = bv;
    dctTb[h * L + p] = bv;
}

// ---------------- fp32 weight -> bf16 with zero pad --------------------------
__global__ __launch_bounds__(BLK) void k_cvt(const float* __restrict__ src,
                                             bft* __restrict__ dst,
                                             int Mr, int Kr, int Kp) {
    int idx = blockIdx.x * BLK + threadIdx.x;
    int m = idx / Kp, k = idx - m * Kp;
    float v = (m < Mr && k < Kr) ? src[(size_t)m * Kr + k] : 0.f;
    dst[idx] = __float2bfloat16(v);
}

// ---------------- w_in -> bf16, rows remapped: f1 at 0..509, f2 at 512..1021 -
__global__ __launch_bounds__(BLK) void k_cvt_ffn(const float* __restrict__ src,
                                                 bft* __restrict__ dst) {
    int idx = blockIdx.x * BLK + threadIdx.x;   // [0, 1024*192)
    int m = idx / Cc, k = idx - m * Cc;
    float v = 0.f;
    if (m < 510) v = src[(size_t)m * Cc + k];
    else if (m >= 512 && m < 1022) v = src[(size_t)(m - 2) * Cc + k];
    dst[idx] = __float2bfloat16(v);
}

// =============================================================================
// Tile LayerNorm: block = 64 pixels x 192 channels via LDS (coalesced global).
// =============================================================================
template <typename TI, bool TRANS>
__global__ __launch_bounds__(BLK) void k_lnt(const TI* __restrict__ x,
                                             const float* __restrict__ w,
                                             const float* __restrict__ b,
                                             bft* __restrict__ out,
                                             long zI, long zO) {
    __shared__ float t[192][65];
    __shared__ float mus[64], rs[64];
    const int tid = threadIdx.x;
    const int s0 = blockIdx.x * 64;
    const TI* xp = x + (size_t)blockIdx.y * zI;
    if constexpr (sizeof(TI) == 4) {
        for (int id = tid; id < 192 * 16; id += BLK) {
            int c = id >> 4, q = id & 15;
            float4 v = *reinterpret_cast<const float4*>(
                (const float*)xp + (size_t)c * S + s0 + q * 4);
            t[c][q * 4 + 0] = v.x; t[c][q * 4 + 1] = v.y;
            t[c][q * 4 + 2] = v.z; t[c][q * 4 + 3] = v.w;
        }
    } else {
        for (int id = tid; id < 192 * 8; id += BLK) {
            int c = id >> 3, q = id & 7;
            uint4 raw = *reinterpret_cast<const uint4*>(
                (const bft*)xp + (size_t)c * S + s0 + q * 8);
            const unsigned short* u = reinterpret_cast<const unsigned short*>(&raw);
#pragma unroll
            for (int e = 0; e < 8; ++e) t[c][q * 8 + e] = bu2f(u[e]);
        }
    }
    __syncthreads();
    {
        int px = tid >> 2, g = tid & 3;
        float sum = 0.f, sq = 0.f;
#pragma unroll
        for (int j = 0; j < 48; ++j) {
            float v = t[g * 48 + j][px];
            sum += v; sq += v * v;
        }
        sum += __shfl_xor(sum, 1); sum += __shfl_xor(sum, 2);
        sq  += __shfl_xor(sq, 1);  sq  += __shfl_xor(sq, 2);
        float mu = sum * (1.f / Cc);
        float var = sq * (1.f / Cc) - mu * mu;
        float r = rsqrtf(var + 1e-5f);
        if (g == 0) { mus[px] = mu; rs[px] = r; }
    }
    __syncthreads();
    bft* op = out + (size_t)blockIdx.y * zO;
    if constexpr (!TRANS) {
        for (int id = tid; id < 192 * 8; id += BLK) {
            int c = id >> 3, q = id & 7;
            float wc = w[c], bc = b[c];
            unsigned short v8[8];
#pragma unroll
            for (int e = 0; e < 8; ++e) {
                int px = q * 8 + e;
                v8[e] = f2bfu((t[c][px] - mus[px]) * rs[px] * wc + bc);
            }
            nt16(op + (size_t)c * S + s0 + q * 8, v8);
        }
    } else {
#pragma unroll
        for (int qq = 0; qq < 3; ++qq) {
            for (int id = tid; id < 512; id += BLK) {
                int s = id >> 3, qlo = id & 7;
                int q = qq * 8 + qlo;
                float mu = mus[s], r = rs[s];
                unsigned short v8[8];
#pragma unroll
                for (int e = 0; e < 8; ++e) {
                    int c = q * 8 + e;
                    v8[e] = f2bfu((t[c][s] - mu) * r * w[c] + b[c]);
                }
                nt16(op + (size_t)(s0 + s) * Cc + q * 8, v8);
            }
        }
    }
}

// ---------------- transpose [Cc][S] -> [S][Cc] (batched via grid.z) ----------
__global__ __launch_bounds__(BLK) void k_tr(const bft* __restrict__ in,
                                            bft* __restrict__ out, long z) {
    __shared__ unsigned short t[32][72];
    const int tid = threadIdx.x;
    const int s0 = blockIdx.x * 64, c0 = blockIdx.y * 32;
    const bft* ip = in + (size_t)blockIdx.z * z;
    bft* op = out + (size_t)blockIdx.z * z;
    {
        int c = tid >> 3, sc = (tid & 7) * 8;
        *reinterpret_cast<uint4*>(&t[c][sc]) =
            *reinterpret_cast<const uint4*>(ip + (size_t)(c0 + c) * S + s0 + sc);
    }
    __syncthreads();
    {
        int s = tid >> 2, cc = (tid & 3) * 8;
        unsigned short v[8];
#pragma unroll
        for (int q = 0; q < 8; ++q) v[q] = t[cc + q][s];
        nt16(op + (size_t)(s0 + s) * Cc + c0 + cc, v);
    }
}

// ---------------- window-tiled-transposed [s*][Cc] -> NCHW spatial -----------
__global__ __launch_bounds__(BLK) void k_w2s(const bft* __restrict__ src,
                                             bft* __restrict__ dst,
                                             long zI, long zO) {
    __shared__ unsigned short t[192][100];
    const int tid = threadIdx.x;
    const int hh = blockIdx.x;
    const int ch0 = blockIdx.y * 96;
    const int bz = blockIdx.z;
    const int h1 = hh >> 3, ii = hh & 7;
    const bft* ip = src + (size_t)bz * zI;
    for (int id = tid; id < 192 * 12; id += BLK) {
        int r = id / 12, q = id - r * 12;
        int w1 = r >> 3, jj = r & 7;
        int s = (h1 * 24 + w1) * 64 + ii * 8 + jj;
        *reinterpret_cast<uint4*>(&t[r][q * 8]) =
            *reinterpret_cast<const uint4*>(ip + (size_t)s * Cc + ch0 + q * 8);
    }
    __syncthreads();
    bft* op = dst + (size_t)bz * zO;
    for (int id = tid; id < 96 * 24; id += BLK) {
        int c = id / 24, q = id - c * 24;
        unsigned short v[8];
#pragma unroll
        for (int e = 0; e < 8; ++e) v[e] = t[q * 8 + e][c];
        nt16(op + (size_t)(ch0 + c) * S + (size_t)hh * L + q * 8, v);
    }
}

// =============================================================================
// Unified MFMA bf16 GEMM. KSTEP=32 + halved restage epilogues (20.5KB LDS),
// non-temporal writeout, no trailing barrier after the last half.
// =============================================================================
template <int WR, int WC, int FM, int FN, int KSTEP, int BMODE, int OMODE,
          bool GSWAP, bool SWIZ, bool AMASK, bool HASBIAS, bool BIASN,
          bool HASRES, typename OutT, typename ResT>
__global__ __launch_bounds__(256) void k_mm(
    const bft* __restrict__ A, int strideA, int Mreal, long zA,
    const bft* __restrict__ B, int strideB, long zB,
    OutT* __restrict__ Out, int strideO, long zO,
    const float* __restrict__ bias,
    const ResT* __restrict__ Res, long zR,
    int K, int rlo, int rhi) {
    static_assert(WR == 2 && WC == 2, "split epilogues assume 2x2 waves");
    constexpr int BM = WR * FM * 16, BN = WC * FN * 16;
    constexpr int AV = KSTEP / 8;
    constexpr int KL = (BM + BN) * (KSTEP + 8);
    constexpr int RSTH = (OMODE == 3) ? (BN / 2) * (BM + 8)
                       : (OMODE == 5 ? (BM / 2) * (BN + 8) : 0);
    constexpr int LDSZ = (KL > RSTH) ? KL : RSTH;
    __shared__ unsigned short lds[LDSZ];
    unsigned short (*Al)[KSTEP + 8] =
        reinterpret_cast<unsigned short(*)[KSTEP + 8]>(lds);
    unsigned short (*Bl)[KSTEP + 8] =
        reinterpret_cast<unsigned short(*)[KSTEP + 8]>(lds + BM * (KSTEP + 8));
    const int tid = threadIdx.x;
    int bx = blockIdx.x, by = blockIdx.y;
    if constexpr (SWIZ) {
        int nbx = gridDim.x, nby = gridDim.y;
        int nwg = nbx * nby;
        int orig = bx + nbx * by;
        int cpx = nwg >> 3;                       // nwg % 8 == 0 by launch
        int swz = (orig & 7) * cpx + (orig >> 3);
        bx = swz % nbx; by = swz / nbx;
    }
    const int n0 = (GSWAP ? by : bx) * BN;
    const int m0 = (GSWAP ? bx : by) * BM;
    const int bz = blockIdx.z;
    const int lane = tid & 63, wv = tid >> 6;
    const int wr = wv / WC, wc = wv % WC;
    const int l15 = lane & 15, l4 = lane >> 4;
    f32x4 acc[FM][FN] = {};

    const bft* Ab = A + (size_t)bz * zA;
    const bft* Bb = B + (size_t)bz * zB;

    for (int k0 = 0; k0 < K; k0 += KSTEP) {
        for (int id = tid; id < BM * AV; id += 256) {
            int row = id / AV, kc = (id % AV) * 8;
            int gm = m0 + row;
            if constexpr (AMASK) {
                uint4 val = make_uint4(0, 0, 0, 0);
                if (gm >= rlo && gm < rhi)
                    val = *reinterpret_cast<const uint4*>(
                        Ab + (size_t)gm * strideA + k0 + kc);
                *reinterpret_cast<uint4*>(&Al[row][kc]) = val;
            } else {
                if (gm >= Mreal) gm = Mreal - 1;
                *reinterpret_cast<uint4*>(&Al[row][kc]) =
                    *reinterpret_cast<const uint4*>(Ab + (size_t)gm * strideA + k0 + kc);
            }
        }
        for (int id = tid; id < BN * AV; id += 256) {
            int row = id / AV, kc = (id % AV) * 8;
            int gn = n0 + row;
            uint4 val;
            if constexpr (BMODE == 2) {
                val = *reinterpret_cast<const uint4*>(
                    Bb + (size_t)gn * strideB + k0 + kc);
            } else {  // BMODE 4: masked row range
                if (gn >= rlo && gn < rhi)
                    val = *reinterpret_cast<const uint4*>(
                        Bb + (size_t)gn * strideB + k0 + kc);
                else
                    val = make_uint4(0, 0, 0, 0);
            }
            *reinterpret_cast<uint4*>(&Bl[row][kc]) = val;
        }
        __syncthreads();
#pragma unroll
        for (int kk = 0; kk < KSTEP / 32; ++kk) {
            bf16x8 af[FM], bf[FN];
#pragma unroll
            for (int i = 0; i < FM; ++i)
                af[i] = *reinterpret_cast<const bf16x8*>(
                    &Al[wr * FM * 16 + i * 16 + l15][kk * 32 + l4 * 8]);
#pragma unroll
            for (int j = 0; j < FN; ++j)
                bf[j] = *reinterpret_cast<const bf16x8*>(
                    &Bl[wc * FN * 16 + j * 16 + l15][kk * 32 + l4 * 8]);
#pragma unroll
            for (int i = 0; i < FM; ++i)
#pragma unroll
                for (int j = 0; j < FN; ++j)
                    acc[i][j] = __builtin_amdgcn_mfma_f32_16x16x32_bf16(
                        af[i], bf[j], acc[i][j], 0, 0, 0);
        }
        __syncthreads();
    }
    if constexpr (OMODE == 3) {
        constexpr int OST = BM + 8;
        constexpr int HBN = BN / 2;                // = FN*16
        unsigned short* Ol = lds;
        constexpr int TPR = BM / 64;
#pragma unroll
        for (int h = 0; h < 2; ++h) {
            if (wc == h) {
#pragma unroll
                for (int i = 0; i < FM; ++i) {
                    int mB = wr * FM * 16 + i * 16 + l4 * 4;
#pragma unroll
                    for (int j = 0; j < FN; ++j) {
                        int nl = j * 16 + l15;     // local n within half
                        unsigned short v[4];
#pragma unroll
                        for (int r = 0; r < 4; ++r) v[r] = f2bfu(acc[i][j][r]);
                        *reinterpret_cast<uint2*>(&Ol[nl * OST + mB]) =
                            *reinterpret_cast<uint2*>(v);
                    }
                }
            }
            __syncthreads();
            for (int row = tid / TPR; row < HBN; row += 256 / TPR) {
                int seg = (tid % TPR) * 64;
                bft* dst = (bft*)Out + (size_t)bz * zO
                         + (size_t)(n0 + h * HBN + row) * strideO + m0 + seg;
                const unsigned short* src = &Ol[row * OST + seg];
#pragma unroll
                for (int q = 0; q < 8; ++q)
                    nt16(dst + q * 8, src + q * 8);
            }
            if (h == 0) __syncthreads();
        }
        return;
    }
    if constexpr (OMODE == 5) {
        constexpr int OST = BN + 8;
        constexpr int HBM = BM / 2;                // = FM*16
        unsigned short* Ol = lds;
        constexpr int TPR = BN / 64;
#pragma unroll
        for (int h = 0; h < 2; ++h) {
            if (wr == h) {
#pragma unroll
                for (int i = 0; i < FM; ++i) {
                    int mBl = i * 16 + l4 * 4;     // local m within half
#pragma unroll
                    for (int j = 0; j < FN; ++j) {
                        int n = wc * FN * 16 + j * 16 + l15;
                        float bn = 0.f;
                        if constexpr (HASBIAS && BIASN) bn = bias[n0 + n];
#pragma unroll
                        for (int r = 0; r < 4; ++r)
                            Ol[(mBl + r) * OST + n] = f2bfu(acc[i][j][r] + bn);
                    }
                }
            }
            __syncthreads();
            for (int row = tid / TPR; row < HBM; row += 256 / TPR) {
                int m = m0 + h * HBM + row;
                if (m >= Mreal) continue;
                int seg = (tid % TPR) * 64;
                bft* dst = (bft*)Out + (size_t)bz * zO
                         + (size_t)m * strideO + n0 + seg;
                const unsigned short* src = &Ol[row * OST + seg];
                if constexpr (HASRES) {
                    const ResT* res = Res + (size_t)bz * zR
                                    + (size_t)m * strideO + n0 + seg;
#pragma unroll
                    for (int q = 0; q < 8; ++q) {
                        uint4 lv = *reinterpret_cast<const uint4*>(src + q * 8);
                        const unsigned short* le =
                            reinterpret_cast<const unsigned short*>(&lv);
                        unsigned short ov[8];
#pragma unroll
                        for (int e = 0; e < 8; ++e)
                            ov[e] = f2bfu(bu2f(le[e]) + ldf(res + q * 8 + e));
                        nt16(dst + q * 8, ov);
                    }
                } else {
#pragma unroll
                    for (int q = 0; q < 8; ++q)
                        nt16(dst + q * 8, src + q * 8);
                }
            }
            if (h == 0) __syncthreads();
        }
        return;
    }
#pragma unroll
    for (int i = 0; i < FM; ++i) {
        int mB = m0 + wr * FM * 16 + i * 16 + l4 * 4;
#pragma unroll
        for (int j = 0; j < FN; ++j) {
            int n = n0 + wc * FN * 16 + j * 16 + l15;
#pragma unroll
            for (int r = 0; r < 4; ++r) {
                int m = mB + r;
                if (m >= Mreal) continue;
                float vv = acc[i][j][r];
                if constexpr (HASBIAS) vv += BIASN ? bias[n] : bias[m];
                size_t idx = (size_t)bz * zO + (size_t)m * strideO + n;
                if constexpr (HASRES)
                    vv += ldf(Res + (size_t)bz * zR + (size_t)m * strideO + n);
                if constexpr (sizeof(OutT) == 4)
                    ntf((float*)Out + idx, vv);
                else
                    stf(Out + idx, vv);
            }
        }
    }
}

// =============================================================================
// Window-row-aligned fused depthwise 3x3 (bank-conflict-free LDS stride 225).
// =============================================================================
__global__ __launch_bounds__(BLK) void k_dwconv3b(const bft* __restrict__ qkv,
                                                  const float* __restrict__ wt,
                                                  bft* __restrict__ q_out,
                                                  bft* __restrict__ k_out,
                                                  bft* __restrict__ v_out,
                                                  long CSl) {
    __shared__ float t[10 * DWS];              // stride 225 == 1 (mod 32)
    const int tid = threadIdx.x;
    const int ch3 = blockIdx.x;                // [0, Bn*576)
    const int wr = blockIdx.y;                 // window row 0..23
    const int b = ch3 / 576, zc = ch3 - b * 576;
    const int z = zc / Cc, ch = zc - z * Cc;
    const int h0 = wr * 8;
    const bft* ip = qkv + (size_t)b * 3 * CSl + (size_t)zc * S;
    for (int id = tid; id < 240; id += BLK) {
        int row = id / 24, q = id - row * 24;
        int gh = h0 - 1 + row;
        float e[8];
        if (gh >= 0 && gh < L) {
            uint4 raw = *reinterpret_cast<const uint4*>(ip + (size_t)gh * L + q * 8);
            const unsigned short* u = reinterpret_cast<const unsigned short*>(&raw);
#pragma unroll
            for (int ee = 0; ee < 8; ++ee) e[ee] = bu2f(u[ee]);
        } else {
#pragma unroll
            for (int ee = 0; ee < 8; ++ee) e[ee] = 0.f;
        }
#pragma unroll
        for (int ee = 0; ee < 8; ++ee) t[row * DWS + 1 + q * 8 + ee] = e[ee];
    }
    if (tid < 10) { t[tid * DWS] = 0.f; t[tid * DWS + 193] = 0.f; }
    __syncthreads();
    if (tid >= 192) return;
    float wv9[9];
#pragma unroll
    for (int i = 0; i < 9; ++i) wv9[i] = wt[(size_t)zc * 9 + i];
    const int wl = tid >> 3;
    const int ii = tid & 7;
    const int w0 = wl * 8;
    float acc[8] = {};
#pragma unroll
    for (int dy = 0; dy < 3; ++dy) {
        const float* rowp = &t[(ii + dy) * DWS + w0];
#pragma unroll
        for (int dx = 0; dx < 3; ++dx) {
            float wgt = wv9[dy * 3 + dx];
#pragma unroll
            for (int jj = 0; jj < 8; ++jj)
                acc[jj] += wgt * rowp[jj + dx];
        }
    }
    bft* base = (z == 0) ? q_out : (z == 1) ? k_out : v_out;
    unsigned short ov[8];
#pragma unroll
    for (int jj = 0; jj < 8; ++jj) ov[jj] = f2bfu(acc[jj]);
    nt16(base + (size_t)b * CSl + (size_t)ch * S
         + (size_t)(wr * 24 + wl) * 64 + ii * 8, ov);
}

// ---------------- window channel attention via MFMA; out = [s*][Cc] ----------
__global__ __launch_bounds__(256) void k_attn_mfma(
    const bft* __restrict__ QW, long zQ,
    const bft* __restrict__ KW, long zK,
    const bft* __restrict__ VW, long zV,
    const float* __restrict__ temp,
    bft* __restrict__ outp, long zO) {
    __shared__ unsigned short qls[4][32 * 66];
    __shared__ unsigned short kls[4][32 * 66];
    __shared__ unsigned short vls[4][32 * 66];
    __shared__ float rqs[4][32], rks[4][32];
    const int tid = threadIdx.x;
    const int wv = tid >> 6, lane = tid & 63;
    const int win = blockIdx.x * 4 + wv;
    const int hd = blockIdx.y;
    const int bz = blockIdx.z;
    const int l15 = lane & 15, l4 = lane >> 4;
    unsigned short* ql = qls[wv];
    unsigned short* kl = kls[wv];
    unsigned short* vl = vls[wv];
    const size_t base = (size_t)(hd * 32) * S + (size_t)win * 64;

#pragma unroll
    for (int i = 0; i < 4; ++i) {
        int c = i * 8 + (lane >> 3), e0 = (lane & 7) * 8;
        size_t g = base + (size_t)c * S + e0;
        uint4 vq = *reinterpret_cast<const uint4*>(QW + (size_t)bz * zQ + g);
        uint4 vk = *reinterpret_cast<const uint4*>(KW + (size_t)bz * zK + g);
        uint4 vvv = *reinterpret_cast<const uint4*>(VW + (size_t)bz * zV + g);
        unsigned int* dq = reinterpret_cast<unsigned int*>(&ql[c * 66 + e0]);
        unsigned int* dk = reinterpret_cast<unsigned int*>(&kl[c * 66 + e0]);
        unsigned int* dv = reinterpret_cast<unsigned int*>(&vl[c * 66 + e0]);
        dq[0] = vq.x; dq[1] = vq.y; dq[2] = vq.z; dq[3] = vq.w;
        dk[0] = vk.x; dk[1] = vk.y; dk[2] = vk.z; dk[3] = vk.w;
        dv[0] = vvv.x; dv[1] = vvv.y; dv[2] = vvv.z; dv[3] = vvv.w;
    }
    __syncthreads();
    {
        int row = lane & 31;
        const unsigned short* src = (lane < 32) ? ql : kl;
        float s = 0.f;
#pragma unroll
        for (int w = 0; w < 32; ++w) {
            unsigned int d = *reinterpret_cast<const unsigned int*>(&src[row * 66 + 2 * w]);
            float a = bu2f((unsigned short)(d & 0xffff));
            float b = bu2f((unsigned short)(d >> 16));
            s += a * a + b * b;
        }
        float r = 1.f / fmaxf(sqrtf(s), 1e-12f);
        if (lane < 32) rqs[wv][row] = r; else rks[wv][row] = r;
    }
    __syncthreads();
    f32x4 at[2][2] = {};
#pragma unroll
    for (int ks = 0; ks < 2; ++ks) {
        bf16x8 aq[2], bk[2];
#pragma unroll
        for (int i = 0; i < 2; ++i)
            aq[i] = ld8(&ql[(i * 16 + l15) * 66 + ks * 32 + l4 * 8]);
#pragma unroll
        for (int j = 0; j < 2; ++j)
            bk[j] = ld8(&kl[(j * 16 + l15) * 66 + ks * 32 + l4 * 8]);
#pragma unroll
        for (int i = 0; i < 2; ++i)
#pragma unroll
            for (int j = 0; j < 2; ++j)
                at[i][j] = __builtin_amdgcn_mfma_f32_16x16x32_bf16(
                    aq[i], bk[j], at[i][j], 0, 0, 0);
    }
    float tpr = temp[hd];
    float rk0 = rks[wv][l15] * tpr, rk1 = rks[wv][16 + l15] * tpr;
    float pr[2][2][4];
#pragma unroll
    for (int i = 0; i < 2; ++i)
#pragma unroll
        for (int r = 0; r < 4; ++r) {
            int c = i * 16 + l4 * 4 + r;
            float rq = rqs[wv][c];
            float v0 = at[i][0][r] * rq * rk0;
            float v1 = at[i][1][r] * rq * rk1;
            float mx = fmaxf(v0, v1);
#pragma unroll
            for (int m = 1; m < 16; m <<= 1) mx = fmaxf(mx, __shfl_xor(mx, m));
            v0 = __expf(v0 - mx);
            v1 = __expf(v1 - mx);
            float sm = v0 + v1;
#pragma unroll
            for (int m = 1; m < 16; m <<= 1) sm += __shfl_xor(sm, m);
            float inv = 1.f / sm;
            pr[i][0][r] = v0 * inv;
            pr[i][1][r] = v1 * inv;
        }
    __syncthreads();
    unsigned short* pl = ql;
#pragma unroll
    for (int i = 0; i < 2; ++i)
#pragma unroll
        for (int j = 0; j < 2; ++j)
#pragma unroll
            for (int r = 0; r < 4; ++r)
                pl[(i * 16 + l4 * 4 + r) * 34 + j * 16 + l15] = f2bfu(pr[i][j][r]);
    __syncthreads();
    bf16x8 ap[2];
#pragma unroll
    for (int i = 0; i < 2; ++i)
        ap[i] = ld8(&pl[(i * 16 + l15) * 34 + l4 * 8]);
    f32x4 o[2][4] = {};
#pragma unroll
    for (int j = 0; j < 4; ++j) {
        unsigned short tv[8];
#pragma unroll
        for (int q = 0; q < 8; ++q)
            tv[q] = vl[(l4 * 8 + q) * 66 + j * 16 + l15];
        bf16x8 bv = *reinterpret_cast<bf16x8*>(tv);
#pragma unroll
        for (int i = 0; i < 2; ++i)
            o[i][j] = __builtin_amdgcn_mfma_f32_16x16x32_bf16(ap[i], bv, o[i][j], 0, 0, 0);
    }
#pragma unroll
    for (int i = 0; i < 2; ++i)
#pragma unroll
        for (int j = 0; j < 4; ++j) {
            int e = j * 16 + l15, cl = i * 16 + l4 * 4;
            unsigned short v[4];
#pragma unroll
            for (int r = 0; r < 4; ++r) v[r] = f2bfu(o[i][j][r]);
            unsigned short* row = ((e < 32) ? kl : vl) + (e & 31) * 40 + cl;
            *reinterpret_cast<uint2*>(row) = *reinterpret_cast<uint2*>(v);
        }
    {
        const unsigned short* row = ((lane < 32) ? kl : vl) + (lane & 31) * 40;
        bft* dst = outp + (size_t)bz * zO + (size_t)(win * 64 + lane) * Cc + hd * 32;
#pragma unroll
        for (int q = 0; q < 4; ++q)
            nt16(dst + q * 8, row + q * 8);
    }
}

// ---------------- FFN gate (transposed, batched): fT -> gT -------------------
__global__ __launch_bounds__(BLK) void k_gateT(const bft* __restrict__ fTg,
                                               const float* __restrict__ wt,
                                               bft* __restrict__ gTg) {
    __shared__ float w1s[64][9];
    __shared__ float w2s[64][9];
    const int tid = threadIdx.x;
    const int cbase = blockIdx.y * 64;
    const bft* fT = fTg + (size_t)blockIdx.z * FTR2 * 1024;
    bft* gT = gTg + (size_t)blockIdx.z * GTR2 * 512;
    for (int id = tid; id < 576; id += BLK) {
        int cl = id / 9, k = id - cl * 9;
        int c = cbase + cl;
        w1s[cl][k] = (c < HID) ? wt[(size_t)c * 9 + k] : 0.f;
        w2s[cl][k] = (c < HID) ? wt[(size_t)(c + HID) * 9 + k] : 0.f;
    }
    __syncthreads();
    int px = blockIdx.x * 32 + (tid >> 3);
    int cgl = (tid & 7) * 8;
    int hc = px / L, w = px - hc * L;
    float a1[8] = {}, a2[8] = {};
#pragma unroll
    for (int dy = 0; dy < 3; ++dy) {
#pragma unroll
        for (int dx = 0; dx < 3; ++dx) {
            int ww = w + dx - 1;
            if (ww < 0 || ww >= L) continue;
            size_t frow = (size_t)((hc + dy) * L + ww) * 1024 + cbase + cgl;
            uint4 u1 = *reinterpret_cast<const uint4*>(fT + frow);
            uint4 u2 = *reinterpret_cast<const uint4*>(fT + frow + 512);
            const unsigned short* e1 = reinterpret_cast<const unsigned short*>(&u1);
            const unsigned short* e2 = reinterpret_cast<const unsigned short*>(&u2);
            int k = dy * 3 + dx;
#pragma unroll
            for (int j = 0; j < 8; ++j) {
                a1[j] += w1s[cgl + j][k] * bu2f(e1[j]);
                a2[j] += w2s[cgl + j][k] * bu2f(e2[j]);
            }
        }
    }
    unsigned short ov[8];
#pragma unroll
    for (int j = 0; j < 8; ++j) {
        float ge = 0.5f * a1[j] * (1.f + erff(a1[j] * 0.70710678118654752f));
        ov[j] = f2bfu(ge * a2[j]);
    }
    nt16(gT + (size_t)px * 512 + cbase + cgl, ov);
}

// -----------------------------------------------------------------------------
extern "C" void kernel_launch(void* const* d_in, const int* in_sizes, int n_in,
                              void* d_out, int out_size, void* d_ws, size_t ws_size,
                              hipStream_t stream) {
    const float* x      = (const float*)d_in[0];
    const float* n1w    = (const float*)d_in[1];
    const float* n1b    = (const float*)d_in[2];
    const float* w_qkv  = (const float*)d_in[3];
    const float* w_dw   = (const float*)d_in[4];
    const float* temp   = (const float*)d_in[5];
    const float* w_proj = (const float*)d_in[6];
    const float* b_proj = (const float*)d_in[7];
    const float* n2w    = (const float*)d_in[8];
    const float* n2b    = (const float*)d_in[9];
    const float* w_in   = (const float*)d_in[10];
    const float* w_dwf  = (const float*)d_in[11];
    const float* w_out  = (const float*)d_in[12];
    float* outp = (float*)d_out;

    // workspace: 236,961,792 bytes
    const long CS = (long)Cc * S;
    const size_t DCT_B = 147456;
    const size_t BUF_B = (size_t)Bn * CS * 2;
    const size_t QKV_B = (size_t)Bn * 3 * CS * 2;
    const size_t WB_B  = 884736;
    const size_t GT_B  = (size_t)Bn * GTR2 * 512 * 2;
    const size_t NEED  = DCT_B + 4 * BUF_B + QKV_B + WB_B + GT_B;
    if (ws_size < NEED) return;

    char* p = (char*)d_ws;
    bft* dctb  = (bft*)p;
    bft* dctTb = dctb + L * L;
    p += DCT_B;
    bft* X1    = (bft*)p;                  p += BUF_B;
    bft* PbB   = (bft*)p;                  p += BUF_B;
    bft* QbB   = (bft*)p;                  p += BUF_B;
    bft* VW    = (bft*)p;                  p += BUF_B;   // v-dwconv output
    bft* QKV   = (bft*)p;                  p += QKV_B;
    bft* w_qkv_b = (bft*)p;
    bft* w_proj_b = w_qkv_b + 576 * 192;
    bft* w_in_b  = w_proj_b + 192 * 192;
    bft* w_out_b = w_in_b + 1024 * 192;
    p += WB_B;
    bft* gT = (bft*)p;                     // [2][GTR2][512]
    bft* fT = QKV;                         // [2][FTR2][1024] (reuses QKV)
    bft* attnT = QKV + CS;

    k_dct_init<<<144, BLK, 0, stream>>>(dctb, dctTb);
    k_cvt<<<432, BLK, 0, stream>>>(w_qkv, w_qkv_b, 576, 192, 192);
    k_cvt<<<144, BLK, 0, stream>>>(w_proj, w_proj_b, 192, 192, 192);
    k_cvt_ffn<<<768, BLK, 0, stream>>>(w_in, w_in_b);
    k_cvt<<<384, BLK, 0, stream>>>(w_out, w_out_b, 192, 510, 512);

    // ---------------- attention branch (both batches per dispatch) -----------
    k_lnt<float, false><<<dim3(S / 64, Bn), BLK, 0, stream>>>(x, n1w, n1b, PbB, CS, CS);
    k_mm<2, 2, 2, 6, 32, 2, 3, false, false, false, false, false, false, bft, float><<<dim3(1, 3, Bn * Cc), 256, 0, stream>>>(
        PbB, L, L, S,  dctb, L, 0,  QbB, L, S,  nullptr, nullptr, 0,  L, 0, 0);
    k_mm<2, 2, 2, 6, 32, 2, 3, false, false, false, false, false, false, bft, float><<<dim3(1, 3, Bn * Cc), 256, 0, stream>>>(
        QbB, L, L, S,  dctb, L, 0,  PbB, L, S,  nullptr, nullptr, 0,  L, 0, 0);
    k_tr<<<dim3(576, 6, Bn), BLK, 0, stream>>>(PbB, QbB, CS);
    // qkv: A=w_qkv (L2), B=ydT rows; GSWAP+SWIZ keeps B slice on one XCD
    k_mm<2, 2, 4, 4, 32, 2, 5, true, true, false, false, false, false, bft, float><<<dim3(5, 288, Bn), 256, 0, stream>>>(
        w_qkv_b, Cc, 576, 0,  QbB, Cc, CS,  QKV, S, 3 * CS,  nullptr, nullptr, 0,  Cc, 0, 0);
    // fused depthwise, window-row aligned (q->PbB, k->QbB, v->VW)
    k_dwconv3b<<<dim3(Bn * 576, 24), BLK, 0, stream>>>(QKV, w_dw, PbB, QbB, VW, CS);
    k_attn_mfma<<<dim3(144, 6, Bn), 256, 0, stream>>>(
        PbB, CS, QbB, CS, VW, CS, temp, attnT, 3 * CS);
    // projT[s*][c] = attnT . w_proj^T + b ; OMODE5 -> full-line row writes
    k_mm<2, 2, 2, 6, 32, 2, 5, false, false, false, true, true, false, bft, float><<<dim3(1, 576, Bn), 256, 0, stream>>>(
        attnT, Cc, S, 3 * CS,  w_proj_b, Cc, 0,  PbB, Cc, CS,  b_proj, (const float*)nullptr, 0,  Cc, 0, 0);
    k_w2s<<<dim3(192, 2, Bn), BLK, 0, stream>>>(PbB, QbB, CS, CS);
    k_mm<2, 2, 2, 6, 32, 2, 3, false, false, false, false, false, false, bft, float><<<dim3(1, 3, Bn * Cc), 256, 0, stream>>>(
        QbB, L, L, S,  dctTb, L, 0,  PbB, L, S,  nullptr, nullptr, 0,  L, 0, 0);
    // G4: OMODE5 + fp32 residual (row-contiguous) -> X1
    k_mm<2, 2, 2, 6, 32, 2, 5, false, false, false, false, false, true, bft, float><<<dim3(1, 3, Bn * Cc), 256, 0, stream>>>(
        dctTb, L, L, 0,  PbB, L, S,  X1, L, S,  nullptr, x, S,  L, 0, 0);

    // ---------------- FFN branch (2 chunks of 96 rows) -----------------------
    k_lnt<bft, true><<<dim3(S / 64, Bn), BLK, 0, stream>>>(X1, n2w, n2b, QbB, CS, CS);
    for (int ck = 0; ck < 2; ++ck) {
        int h0 = ck * CH2;
        long off = (long)(h0 - 1) * L;
        int rlo = (ck == 0) ? L : 0;
        int rhi = (ck == 1) ? (FTR2 - L) : FTR2;
        // fT: A=w_in, B=zT masked rows; GSWAP+SWIZ
        k_mm<2, 2, 4, 4, 32, 4, 3, true, true, false, false, false, false, bft, float><<<dim3(8, 147, Bn), 256, 0, stream>>>(
            w_in_b, Cc, 1024, 0,  QbB + off * Cc, Cc, CS,  fT, 1024, (long)FTR2 * 1024,
            nullptr, nullptr, 0,  Cc, rlo, rhi);
        k_gateT<<<dim3(GTR2 / 32, 8, Bn), BLK, 0, stream>>>(fT, w_dwf, gT);
        // wout: A=w_out, B=gT rows; GSWAP+SWIZ, fp32 nt stores
        k_mm<2, 2, 2, 4, 32, 2, 0, true, true, false, false, false, true, float, bft><<<dim3(3, 144, Bn), 256, 0, stream>>>(
            w_out_b, 512, 192, 0,  gT, 512, (long)GTR2 * 512,
            outp + (size_t)ck * GTR2, S, CS,
            nullptr, X1 + (size_t)ck * GTR2, CS,  512, 0, 0);
    }
}

// Round 27
// 628.472 us; speedup vs baseline: 1.8645x; 1.8645x over previous
//
#include <hip/hip_runtime.h>
#include <hip/hip_bf16.h>

typedef __hip_bfloat16 bft;
typedef __attribute__((ext_vector_type(8))) short bf16x8;
typedef __attribute__((ext_vector_type(4))) float f32x4;

#define BLK 256
static constexpr int Cc = 192;     // channels
static constexpr int L  = 192;     // H = W
static constexpr int S  = 36864;   // L*L
static constexpr int Bn = 2;       // batch
static constexpr int HID = 510;    // int(192*2.66)
static constexpr int CH2 = 96;     // FFN chunk height (image rows)
static constexpr int FTR2 = (CH2 + 2) * L;   // 18816 fT rows (with halo)
static constexpr int GTR2 = CH2 * L;         // 18432 gT rows
static constexpr int DWS = 225;    // dwconv LDS row stride (== 1 mod 32)
static constexpr double PI_D = 3.141592653589793238462643383279502884;

__device__ __forceinline__ float ldf(const float* p) { return *p; }
__device__ __forceinline__ float ldf(const bft* p)   { return __bfloat162float(*p); }
__device__ __forceinline__ void  stf(float* p, float v) { *p = v; }
__device__ __forceinline__ void  stf(bft* p, float v)   { *p = __float2bfloat16(v); }
__device__ __forceinline__ unsigned short f2bfu(float f) {
    bft h = __float2bfloat16(f);
    return *reinterpret_cast<const unsigned short*>(&h);
}
__device__ __forceinline__ float bu2f(unsigned short u) {
    unsigned int x = (unsigned int)u << 16;
    return __uint_as_float(x);
}
__device__ __forceinline__ bf16x8 ld8(const unsigned short* p) {   // 4B-aligned
    union { unsigned int u[4]; bf16x8 v; } t;
    const unsigned int* q = reinterpret_cast<const unsigned int*>(p);
    t.u[0] = q[0]; t.u[1] = q[1]; t.u[2] = q[2]; t.u[3] = q[3];
    return t.v;
}
// LDS-only barrier: orders ds ops without draining in-flight global stores
// (avoids __syncthreads' implicit s_waitcnt vmcnt(0) — the store-drain stall).
__device__ __forceinline__ void softbar() {
    asm volatile("s_waitcnt lgkmcnt(0)" ::: "memory");
    __builtin_amdgcn_sched_barrier(0);
    __builtin_amdgcn_s_barrier();
}

// ---------------- DCT matrix init -> bf16 direct + transposed ----------------
__global__ __launch_bounds__(BLK) void k_dct_init(bft* __restrict__ dctb,
                                                  bft* __restrict__ dctTb) {
    int idx = blockIdx.x * BLK + threadIdx.x;
    if (idx >= L * L) return;
    int p = idx / L, h = idx - p * L;
    double v = (p == 0) ? sqrt(1.0 / L)
                        : cos(PI_D * p * (2 * h + 1) / (2.0 * L)) * sqrt(2.0 / L);
    bft bv = __float2bfloat16((float)v);
    dctb[p * L + h] = bv;
    dctTb[h * L + p] = bv;
}

// ---------------- fp32 weight -> bf16 with zero pad --------------------------
__global__ __launch_bounds__(BLK) void k_cvt(const float* __restrict__ src,
                                             bft* __restrict__ dst,
                                             int Mr, int Kr, int Kp) {
    int idx = blockIdx.x * BLK + threadIdx.x;
    int m = idx / Kp, k = idx - m * Kp;
    float v = (m < Mr && k < Kr) ? src[(size_t)m * Kr + k] : 0.f;
    dst[idx] = __float2bfloat16(v);
}

// ---------------- w_in -> bf16, rows remapped: f1 at 0..509, f2 at 512..1021 -
__global__ __launch_bounds__(BLK) void k_cvt_ffn(const float* __restrict__ src,
                                                 bft* __restrict__ dst) {
    int idx = blockIdx.x * BLK + threadIdx.x;   // [0, 1024*192)
    int m = idx / Cc, k = idx - m * Cc;
    float v = 0.f;
    if (m < 510) v = src[(size_t)m * Cc + k];
    else if (m >= 512 && m < 1022) v = src[(size_t)(m - 2) * Cc + k];
    dst[idx] = __float2bfloat16(v);
}

// =============================================================================
// Tile LayerNorm: block = 64 pixels x 192 channels via LDS (coalesced global).
// =============================================================================
template <typename TI, bool TRANS>
__global__ __launch_bounds__(BLK) void k_lnt(const TI* __restrict__ x,
                                             const float* __restrict__ w,
                                             const float* __restrict__ b,
                                             bft* __restrict__ out,
                                             long zI, long zO) {
    __shared__ float t[192][65];
    __shared__ float mus[64], rs[64];
    const int tid = threadIdx.x;
    const int s0 = blockIdx.x * 64;
    const TI* xp = x + (size_t)blockIdx.y * zI;
    if constexpr (sizeof(TI) == 4) {
        for (int id = tid; id < 192 * 16; id += BLK) {
            int c = id >> 4, q = id & 15;
            float4 v = *reinterpret_cast<const float4*>(
                (const float*)xp + (size_t)c * S + s0 + q * 4);
            t[c][q * 4 + 0] = v.x; t[c][q * 4 + 1] = v.y;
            t[c][q * 4 + 2] = v.z; t[c][q * 4 + 3] = v.w;
        }
    } else {
        for (int id = tid; id < 192 * 8; id += BLK) {
            int c = id >> 3, q = id & 7;
            uint4 raw = *reinterpret_cast<const uint4*>(
                (const bft*)xp + (size_t)c * S + s0 + q * 8);
            const unsigned short* u = reinterpret_cast<const unsigned short*>(&raw);
#pragma unroll
            for (int e = 0; e < 8; ++e) t[c][q * 8 + e] = bu2f(u[e]);
        }
    }
    __syncthreads();
    {
        int px = tid >> 2, g = tid & 3;
        float sum = 0.f, sq = 0.f;
#pragma unroll
        for (int j = 0; j < 48; ++j) {
            float v = t[g * 48 + j][px];
            sum += v; sq += v * v;
        }
        sum += __shfl_xor(sum, 1); sum += __shfl_xor(sum, 2);
        sq  += __shfl_xor(sq, 1);  sq  += __shfl_xor(sq, 2);
        float mu = sum * (1.f / Cc);
        float var = sq * (1.f / Cc) - mu * mu;
        float r = rsqrtf(var + 1e-5f);
        if (g == 0) { mus[px] = mu; rs[px] = r; }
    }
    __syncthreads();
    bft* op = out + (size_t)blockIdx.y * zO;
    if constexpr (!TRANS) {
        for (int id = tid; id < 192 * 8; id += BLK) {
            int c = id >> 3, q = id & 7;
            float wc = w[c], bc = b[c];
            unsigned short v8[8];
#pragma unroll
            for (int e = 0; e < 8; ++e) {
                int px = q * 8 + e;
                v8[e] = f2bfu((t[c][px] - mus[px]) * rs[px] * wc + bc);
            }
            *reinterpret_cast<uint4*>(op + (size_t)c * S + s0 + q * 8) =
                *reinterpret_cast<uint4*>(v8);
        }
    } else {
#pragma unroll
        for (int qq = 0; qq < 3; ++qq) {
            for (int id = tid; id < 512; id += BLK) {
                int s = id >> 3, qlo = id & 7;
                int q = qq * 8 + qlo;
                float mu = mus[s], r = rs[s];
                unsigned short v8[8];
#pragma unroll
                for (int e = 0; e < 8; ++e) {
                    int c = q * 8 + e;
                    v8[e] = f2bfu((t[c][s] - mu) * r * w[c] + b[c]);
                }
                *reinterpret_cast<uint4*>(op + (size_t)(s0 + s) * Cc + q * 8) =
                    *reinterpret_cast<uint4*>(v8);
            }
        }
    }
}

// ---------------- transpose [Cc][S] -> [S][Cc] (batched via grid.z) ----------
__global__ __launch_bounds__(BLK) void k_tr(const bft* __restrict__ in,
                                            bft* __restrict__ out, long z) {
    __shared__ unsigned short t[32][72];
    const int tid = threadIdx.x;
    const int s0 = blockIdx.x * 64, c0 = blockIdx.y * 32;
    const bft* ip = in + (size_t)blockIdx.z * z;
    bft* op = out + (size_t)blockIdx.z * z;
    {
        int c = tid >> 3, sc = (tid & 7) * 8;
        *reinterpret_cast<uint4*>(&t[c][sc]) =
            *reinterpret_cast<const uint4*>(ip + (size_t)(c0 + c) * S + s0 + sc);
    }
    __syncthreads();
    {
        int s = tid >> 2, cc = (tid & 3) * 8;
        unsigned short v[8];
#pragma unroll
        for (int q = 0; q < 8; ++q) v[q] = t[cc + q][s];
        *reinterpret_cast<uint4*>(op + (size_t)(s0 + s) * Cc + c0 + cc) =
            *reinterpret_cast<uint4*>(v);
    }
}

// ---------------- window-tiled-transposed [s*][Cc] -> NCHW spatial -----------
__global__ __launch_bounds__(BLK) void k_w2s(const bft* __restrict__ src,
                                             bft* __restrict__ dst,
                                             long zI, long zO) {
    __shared__ unsigned short t[192][100];
    const int tid = threadIdx.x;
    const int hh = blockIdx.x;
    const int ch0 = blockIdx.y * 96;
    const int bz = blockIdx.z;
    const int h1 = hh >> 3, ii = hh & 7;
    const bft* ip = src + (size_t)bz * zI;
    for (int id = tid; id < 192 * 12; id += BLK) {
        int r = id / 12, q = id - r * 12;
        int w1 = r >> 3, jj = r & 7;
        int s = (h1 * 24 + w1) * 64 + ii * 8 + jj;
        *reinterpret_cast<uint4*>(&t[r][q * 8]) =
            *reinterpret_cast<const uint4*>(ip + (size_t)s * Cc + ch0 + q * 8);
    }
    __syncthreads();
    bft* op = dst + (size_t)bz * zO;
    for (int id = tid; id < 96 * 24; id += BLK) {
        int c = id / 24, q = id - c * 24;
        unsigned short v[8];
#pragma unroll
        for (int e = 0; e < 8; ++e) v[e] = t[q * 8 + e][c];
        *reinterpret_cast<uint4*>(op + (size_t)(ch0 + c) * S + (size_t)hh * L + q * 8) =
            *reinterpret_cast<uint4*>(v);
    }
}

// =============================================================================
// Unified MFMA bf16 GEMM. KSTEP=32 + halved restage epilogues (20.5KB LDS).
// Epilogue barriers are LDS-only (softbar) so global stores stay in flight;
// no trailing barrier after the last half.
// =============================================================================
template <int WR, int WC, int FM, int FN, int KSTEP, int BMODE, int OMODE,
          bool GSWAP, bool SWIZ, bool AMASK, bool HASBIAS, bool BIASN,
          bool HASRES, typename OutT, typename ResT>
__global__ __launch_bounds__(256) void k_mm(
    const bft* __restrict__ A, int strideA, int Mreal, long zA,
    const bft* __restrict__ B, int strideB, long zB,
    OutT* __restrict__ Out, int strideO, long zO,
    const float* __restrict__ bias,
    const ResT* __restrict__ Res, long zR,
    int K, int rlo, int rhi) {
    static_assert(WR == 2 && WC == 2, "split epilogues assume 2x2 waves");
    constexpr int BM = WR * FM * 16, BN = WC * FN * 16;
    constexpr int AV = KSTEP / 8;
    constexpr int KL = (BM + BN) * (KSTEP + 8);
    constexpr int RSTH = (OMODE == 3) ? (BN / 2) * (BM + 8)
                       : (OMODE == 5 ? (BM / 2) * (BN + 8) : 0);
    constexpr int LDSZ = (KL > RSTH) ? KL : RSTH;
    __shared__ unsigned short lds[LDSZ];
    unsigned short (*Al)[KSTEP + 8] =
        reinterpret_cast<unsigned short(*)[KSTEP + 8]>(lds);
    unsigned short (*Bl)[KSTEP + 8] =
        reinterpret_cast<unsigned short(*)[KSTEP + 8]>(lds + BM * (KSTEP + 8));
    const int tid = threadIdx.x;
    int bx = blockIdx.x, by = blockIdx.y;
    if constexpr (SWIZ) {
        int nbx = gridDim.x, nby = gridDim.y;
        int nwg = nbx * nby;
        int orig = bx + nbx * by;
        int cpx = nwg >> 3;                       // nwg % 8 == 0 by launch
        int swz = (orig & 7) * cpx + (orig >> 3);
        bx = swz % nbx; by = swz / nbx;
    }
    const int n0 = (GSWAP ? by : bx) * BN;
    const int m0 = (GSWAP ? bx : by) * BM;
    const int bz = blockIdx.z;
    const int lane = tid & 63, wv = tid >> 6;
    const int wr = wv / WC, wc = wv % WC;
    const int l15 = lane & 15, l4 = lane >> 4;
    f32x4 acc[FM][FN] = {};

    const bft* Ab = A + (size_t)bz * zA;
    const bft* Bb = B + (size_t)bz * zB;

    for (int k0 = 0; k0 < K; k0 += KSTEP) {
        for (int id = tid; id < BM * AV; id += 256) {
            int row = id / AV, kc = (id % AV) * 8;
            int gm = m0 + row;
            if constexpr (AMASK) {
                uint4 val = make_uint4(0, 0, 0, 0);
                if (gm >= rlo && gm < rhi)
                    val = *reinterpret_cast<const uint4*>(
                        Ab + (size_t)gm * strideA + k0 + kc);
                *reinterpret_cast<uint4*>(&Al[row][kc]) = val;
            } else {
                if (gm >= Mreal) gm = Mreal - 1;
                *reinterpret_cast<uint4*>(&Al[row][kc]) =
                    *reinterpret_cast<const uint4*>(Ab + (size_t)gm * strideA + k0 + kc);
            }
        }
        for (int id = tid; id < BN * AV; id += 256) {
            int row = id / AV, kc = (id % AV) * 8;
            int gn = n0 + row;
            uint4 val;
            if constexpr (BMODE == 2) {
                val = *reinterpret_cast<const uint4*>(
                    Bb + (size_t)gn * strideB + k0 + kc);
            } else {  // BMODE 4: masked row range
                if (gn >= rlo && gn < rhi)
                    val = *reinterpret_cast<const uint4*>(
                        Bb + (size_t)gn * strideB + k0 + kc);
                else
                    val = make_uint4(0, 0, 0, 0);
            }
            *reinterpret_cast<uint4*>(&Bl[row][kc]) = val;
        }
        __syncthreads();
#pragma unroll
        for (int kk = 0; kk < KSTEP / 32; ++kk) {
            bf16x8 af[FM], bf[FN];
#pragma unroll
            for (int i = 0; i < FM; ++i)
                af[i] = *reinterpret_cast<const bf16x8*>(
                    &Al[wr * FM * 16 + i * 16 + l15][kk * 32 + l4 * 8]);
#pragma unroll
            for (int j = 0; j < FN; ++j)
                bf[j] = *reinterpret_cast<const bf16x8*>(
                    &Bl[wc * FN * 16 + j * 16 + l15][kk * 32 + l4 * 8]);
#pragma unroll
            for (int i = 0; i < FM; ++i)
#pragma unroll
                for (int j = 0; j < FN; ++j)
                    acc[i][j] = __builtin_amdgcn_mfma_f32_16x16x32_bf16(
                        af[i], bf[j], acc[i][j], 0, 0, 0);
        }
        __syncthreads();
    }
    if constexpr (OMODE == 3) {
        constexpr int OST = BM + 8;
        constexpr int HBN = BN / 2;                // = FN*16
        unsigned short* Ol = lds;
        constexpr int TPR = BM / 64;
#pragma unroll
        for (int h = 0; h < 2; ++h) {
            if (wc == h) {
#pragma unroll
                for (int i = 0; i < FM; ++i) {
                    int mB = wr * FM * 16 + i * 16 + l4 * 4;
#pragma unroll
                    for (int j = 0; j < FN; ++j) {
                        int nl = j * 16 + l15;     // local n within half
                        unsigned short v[4];
#pragma unroll
                        for (int r = 0; r < 4; ++r) v[r] = f2bfu(acc[i][j][r]);
                        *reinterpret_cast<uint2*>(&Ol[nl * OST + mB]) =
                            *reinterpret_cast<uint2*>(v);
                    }
                }
            }
            softbar();
            for (int row = tid / TPR; row < HBN; row += 256 / TPR) {
                int seg = (tid % TPR) * 64;
                bft* dst = (bft*)Out + (size_t)bz * zO
                         + (size_t)(n0 + h * HBN + row) * strideO + m0 + seg;
                const unsigned short* src = &Ol[row * OST + seg];
#pragma unroll
                for (int q = 0; q < 8; ++q)
                    *reinterpret_cast<uint4*>(dst + q * 8) =
                        *reinterpret_cast<const uint4*>(src + q * 8);
            }
            if (h == 0) softbar();
        }
        return;
    }
    if constexpr (OMODE == 5) {
        constexpr int OST = BN + 8;
        constexpr int HBM = BM / 2;                // = FM*16
        unsigned short* Ol = lds;
        constexpr int TPR = BN / 64;
#pragma unroll
        for (int h = 0; h < 2; ++h) {
            if (wr == h) {
#pragma unroll
                for (int i = 0; i < FM; ++i) {
                    int mBl = i * 16 + l4 * 4;     // local m within half
#pragma unroll
                    for (int j = 0; j < FN; ++j) {
                        int n = wc * FN * 16 + j * 16 + l15;
                        float bn = 0.f;
                        if constexpr (HASBIAS && BIASN) bn = bias[n0 + n];
#pragma unroll
                        for (int r = 0; r < 4; ++r)
                            Ol[(mBl + r) * OST + n] = f2bfu(acc[i][j][r] + bn);
                    }
                }
            }
            softbar();
            for (int row = tid / TPR; row < HBM; row += 256 / TPR) {
                int m = m0 + h * HBM + row;
                if (m >= Mreal) continue;
                int seg = (tid % TPR) * 64;
                bft* dst = (bft*)Out + (size_t)bz * zO
                         + (size_t)m * strideO + n0 + seg;
                const unsigned short* src = &Ol[row * OST + seg];
                if constexpr (HASRES) {
                    const ResT* res = Res + (size_t)bz * zR
                                    + (size_t)m * strideO + n0 + seg;
#pragma unroll
                    for (int q = 0; q < 8; ++q) {
                        uint4 lv = *reinterpret_cast<const uint4*>(src + q * 8);
                        const unsigned short* le =
                            reinterpret_cast<const unsigned short*>(&lv);
                        unsigned short ov[8];
#pragma unroll
                        for (int e = 0; e < 8; ++e)
                            ov[e] = f2bfu(bu2f(le[e]) + ldf(res + q * 8 + e));
                        *reinterpret_cast<uint4*>(dst + q * 8) =
                            *reinterpret_cast<uint4*>(ov);
                    }
                } else {
#pragma unroll
                    for (int q = 0; q < 8; ++q)
                        *reinterpret_cast<uint4*>(dst + q * 8) =
                            *reinterpret_cast<const uint4*>(src + q * 8);
                }
            }
            if (h == 0) softbar();
        }
        return;
    }
#pragma unroll
    for (int i = 0; i < FM; ++i) {
        int mB = m0 + wr * FM * 16 + i * 16 + l4 * 4;
#pragma unroll
        for (int j = 0; j < FN; ++j) {
            int n = n0 + wc * FN * 16 + j * 16 + l15;
#pragma unroll
            for (int r = 0; r < 4; ++r) {
                int m = mB + r;
                if (m >= Mreal) continue;
                float vv = acc[i][j][r];
                if constexpr (HASBIAS) vv += BIASN ? bias[n] : bias[m];
                size_t idx = (size_t)bz * zO + (size_t)m * strideO + n;
                if constexpr (HASRES)
                    vv += ldf(Res + (size_t)bz * zR + (size_t)m * strideO + n);
                stf(Out + idx, vv);
            }
        }
    }
}

// =============================================================================
// Window-row-aligned fused depthwise 3x3 (bank-conflict-free LDS stride 225).
// =============================================================================
__global__ __launch_bounds__(BLK) void k_dwconv3b(const bft* __restrict__ qkv,
                                                  const float* __restrict__ wt,
                                                  bft* __restrict__ q_out,
                                                  bft* __restrict__ k_out,
                                                  bft* __restrict__ v_out,
                                                  long CSl) {
    __shared__ float t[10 * DWS];              // stride 225 == 1 (mod 32)
    const int tid = threadIdx.x;
    const int ch3 = blockIdx.x;                // [0, Bn*576)
    const int wr = blockIdx.y;                 // window row 0..23
    const int b = ch3 / 576, zc = ch3 - b * 576;
    const int z = zc / Cc, ch = zc - z * Cc;
    const int h0 = wr * 8;
    const bft* ip = qkv + (size_t)b * 3 * CSl + (size_t)zc * S;
    for (int id = tid; id < 240; id += BLK) {
        int row = id / 24, q = id - row * 24;
        int gh = h0 - 1 + row;
        float e[8];
        if (gh >= 0 && gh < L) {
            uint4 raw = *reinterpret_cast<const uint4*>(ip + (size_t)gh * L + q * 8);
            const unsigned short* u = reinterpret_cast<const unsigned short*>(&raw);
#pragma unroll
            for (int ee = 0; ee < 8; ++ee) e[ee] = bu2f(u[ee]);
        } else {
#pragma unroll
            for (int ee = 0; ee < 8; ++ee) e[ee] = 0.f;
        }
#pragma unroll
        for (int ee = 0; ee < 8; ++ee) t[row * DWS + 1 + q * 8 + ee] = e[ee];
    }
    if (tid < 10) { t[tid * DWS] = 0.f; t[tid * DWS + 193] = 0.f; }
    __syncthreads();
    if (tid >= 192) return;
    float wv9[9];
#pragma unroll
    for (int i = 0; i < 9; ++i) wv9[i] = wt[(size_t)zc * 9 + i];
    const int wl = tid >> 3;
    const int ii = tid & 7;
    const int w0 = wl * 8;
    float acc[8] = {};
#pragma unroll
    for (int dy = 0; dy < 3; ++dy) {
        const float* rowp = &t[(ii + dy) * DWS + w0];
#pragma unroll
        for (int dx = 0; dx < 3; ++dx) {
            float wgt = wv9[dy * 3 + dx];
#pragma unroll
            for (int jj = 0; jj < 8; ++jj)
                acc[jj] += wgt * rowp[jj + dx];
        }
    }
    bft* base = (z == 0) ? q_out : (z == 1) ? k_out : v_out;
    unsigned short ov[8];
#pragma unroll
    for (int jj = 0; jj < 8; ++jj) ov[jj] = f2bfu(acc[jj]);
    *reinterpret_cast<uint4*>(base + (size_t)b * CSl + (size_t)ch * S
                              + (size_t)(wr * 24 + wl) * 64 + ii * 8) =
        *reinterpret_cast<uint4*>(ov);
}

// ---------------- window channel attention via MFMA; out = [s*][Cc] ----------
__global__ __launch_bounds__(256) void k_attn_mfma(
    const bft* __restrict__ QW, long zQ,
    const bft* __restrict__ KW, long zK,
    const bft* __restrict__ VW, long zV,
    const float* __restrict__ temp,
    bft* __restrict__ outp, long zO) {
    __shared__ unsigned short qls[4][32 * 66];
    __shared__ unsigned short kls[4][32 * 66];
    __shared__ unsigned short vls[4][32 * 66];
    __shared__ float rqs[4][32], rks[4][32];
    const int tid = threadIdx.x;
    const int wv = tid >> 6, lane = tid & 63;
    const int win = blockIdx.x * 4 + wv;
    const int hd = blockIdx.y;
    const int bz = blockIdx.z;
    const int l15 = lane & 15, l4 = lane >> 4;
    unsigned short* ql = qls[wv];
    unsigned short* kl = kls[wv];
    unsigned short* vl = vls[wv];
    const size_t base = (size_t)(hd * 32) * S + (size_t)win * 64;

#pragma unroll
    for (int i = 0; i < 4; ++i) {
        int c = i * 8 + (lane >> 3), e0 = (lane & 7) * 8;
        size_t g = base + (size_t)c * S + e0;
        uint4 vq = *reinterpret_cast<const uint4*>(QW + (size_t)bz * zQ + g);
        uint4 vk = *reinterpret_cast<const uint4*>(KW + (size_t)bz * zK + g);
        uint4 vvv = *reinterpret_cast<const uint4*>(VW + (size_t)bz * zV + g);
        unsigned int* dq = reinterpret_cast<unsigned int*>(&ql[c * 66 + e0]);
        unsigned int* dk = reinterpret_cast<unsigned int*>(&kl[c * 66 + e0]);
        unsigned int* dv = reinterpret_cast<unsigned int*>(&vl[c * 66 + e0]);
        dq[0] = vq.x; dq[1] = vq.y; dq[2] = vq.z; dq[3] = vq.w;
        dk[0] = vk.x; dk[1] = vk.y; dk[2] = vk.z; dk[3] = vk.w;
        dv[0] = vvv.x; dv[1] = vvv.y; dv[2] = vvv.z; dv[3] = vvv.w;
    }
    __syncthreads();
    {
        int row = lane & 31;
        const unsigned short* src = (lane < 32) ? ql : kl;
        float s = 0.f;
#pragma unroll
        for (int w = 0; w < 32; ++w) {
            unsigned int d = *reinterpret_cast<const unsigned int*>(&src[row * 66 + 2 * w]);
            float a = bu2f((unsigned short)(d & 0xffff));
            float b = bu2f((unsigned short)(d >> 16));
            s += a * a + b * b;
        }
        float r = 1.f / fmaxf(sqrtf(s), 1e-12f);
        if (lane < 32) rqs[wv][row] = r; else rks[wv][row] = r;
    }
    __syncthreads();
    f32x4 at[2][2] = {};
#pragma unroll
    for (int ks = 0; ks < 2; ++ks) {
        bf16x8 aq[2], bk[2];
#pragma unroll
        for (int i = 0; i < 2; ++i)
            aq[i] = ld8(&ql[(i * 16 + l15) * 66 + ks * 32 + l4 * 8]);
#pragma unroll
        for (int j = 0; j < 2; ++j)
            bk[j] = ld8(&kl[(j * 16 + l15) * 66 + ks * 32 + l4 * 8]);
#pragma unroll
        for (int i = 0; i < 2; ++i)
#pragma unroll
            for (int j = 0; j < 2; ++j)
                at[i][j] = __builtin_amdgcn_mfma_f32_16x16x32_bf16(
                    aq[i], bk[j], at[i][j], 0, 0, 0);
    }
    float tpr = temp[hd];
    float rk0 = rks[wv][l15] * tpr, rk1 = rks[wv][16 + l15] * tpr;
    float pr[2][2][4];
#pragma unroll
    for (int i = 0; i < 2; ++i)
#pragma unroll
        for (int r = 0; r < 4; ++r) {
            int c = i * 16 + l4 * 4 + r;
            float rq = rqs[wv][c];
            float v0 = at[i][0][r] * rq * rk0;
            float v1 = at[i][1][r] * rq * rk1;
            float mx = fmaxf(v0, v1);
#pragma unroll
            for (int m = 1; m < 16; m <<= 1) mx = fmaxf(mx, __shfl_xor(mx, m));
            v0 = __expf(v0 - mx);
            v1 = __expf(v1 - mx);
            float sm = v0 + v1;
#pragma unroll
            for (int m = 1; m < 16; m <<= 1) sm += __shfl_xor(sm, m);
            float inv = 1.f / sm;
            pr[i][0][r] = v0 * inv;
            pr[i][1][r] = v1 * inv;
        }
    __syncthreads();
    unsigned short* pl = ql;
#pragma unroll
    for (int i = 0; i < 2; ++i)
#pragma unroll
        for (int j = 0; j < 2; ++j)
#pragma unroll
            for (int r = 0; r < 4; ++r)
                pl[(i * 16 + l4 * 4 + r) * 34 + j * 16 + l15] = f2bfu(pr[i][j][r]);
    __syncthreads();
    bf16x8 ap[2];
#pragma unroll
    for (int i = 0; i < 2; ++i)
        ap[i] = ld8(&pl[(i * 16 + l15) * 34 + l4 * 8]);
    f32x4 o[2][4] = {};
#pragma unroll
    for (int j = 0; j < 4; ++j) {
        unsigned short tv[8];
#pragma unroll
        for (int q = 0; q < 8; ++q)
            tv[q] = vl[(l4 * 8 + q) * 66 + j * 16 + l15];
        bf16x8 bv = *reinterpret_cast<bf16x8*>(tv);
#pragma unroll
        for (int i = 0; i < 2; ++i)
            o[i][j] = __builtin_amdgcn_mfma_f32_16x16x32_bf16(ap[i], bv, o[i][j], 0, 0, 0);
    }
#pragma unroll
    for (int i = 0; i < 2; ++i)
#pragma unroll
        for (int j = 0; j < 4; ++j) {
            int e = j * 16 + l15, cl = i * 16 + l4 * 4;
            unsigned short v[4];
#pragma unroll
            for (int r = 0; r < 4; ++r) v[r] = f2bfu(o[i][j][r]);
            unsigned short* row = ((e < 32) ? kl : vl) + (e & 31) * 40 + cl;
            *reinterpret_cast<uint2*>(row) = *reinterpret_cast<uint2*>(v);
        }
    {
        const unsigned short* row = ((lane < 32) ? kl : vl) + (lane & 31) * 40;
        bft* dst = outp + (size_t)bz * zO + (size_t)(win * 64 + lane) * Cc + hd * 32;
#pragma unroll
        for (int q = 0; q < 4; ++q)
            *reinterpret_cast<uint4*>(dst + q * 8) =
                *reinterpret_cast<const uint4*>(row + q * 8);
    }
}

// ---------------- FFN gate (transposed, batched): fT -> gT -------------------
__global__ __launch_bounds__(BLK) void k_gateT(const bft* __restrict__ fTg,
                                               const float* __restrict__ wt,
                                               bft* __restrict__ gTg) {
    __shared__ float w1s[64][9];
    __shared__ float w2s[64][9];
    const int tid = threadIdx.x;
    const int cbase = blockIdx.y * 64;
    const bft* fT = fTg + (size_t)blockIdx.z * FTR2 * 1024;
    bft* gT = gTg + (size_t)blockIdx.z * GTR2 * 512;
    for (int id = tid; id < 576; id += BLK) {
        int cl = id / 9, k = id - cl * 9;
        int c = cbase + cl;
        w1s[cl][k] = (c < HID) ? wt[(size_t)c * 9 + k] : 0.f;
        w2s[cl][k] = (c < HID) ? wt[(size_t)(c + HID) * 9 + k] : 0.f;
    }
    __syncthreads();
    int px = blockIdx.x * 32 + (tid >> 3);
    int cgl = (tid & 7) * 8;
    int hc = px / L, w = px - hc * L;
    float a1[8] = {}, a2[8] = {};
#pragma unroll
    for (int dy = 0; dy < 3; ++dy) {
#pragma unroll
        for (int dx = 0; dx < 3; ++dx) {
            int ww = w + dx - 1;
            if (ww < 0 || ww >= L) continue;
            size_t frow = (size_t)((hc + dy) * L + ww) * 1024 + cbase + cgl;
            uint4 u1 = *reinterpret_cast<const uint4*>(fT + frow);
            uint4 u2 = *reinterpret_cast<const uint4*>(fT + frow + 512);
            const unsigned short* e1 = reinterpret_cast<const unsigned short*>(&u1);
            const unsigned short* e2 = reinterpret_cast<const unsigned short*>(&u2);
            int k = dy * 3 + dx;
#pragma unroll
            for (int j = 0; j < 8; ++j) {
                a1[j] += w1s[cgl + j][k] * bu2f(e1[j]);
                a2[j] += w2s[cgl + j][k] * bu2f(e2[j]);
            }
        }
    }
    unsigned short ov[8];
#pragma unroll
    for (int j = 0; j < 8; ++j) {
        float ge = 0.5f * a1[j] * (1.f + erff(a1[j] * 0.70710678118654752f));
        ov[j] = f2bfu(ge * a2[j]);
    }
    *reinterpret_cast<uint4*>(gT + (size_t)px * 512 + cbase + cgl) =
        *reinterpret_cast<uint4*>(ov);
}

// -----------------------------------------------------------------------------
extern "C" void kernel_launch(void* const* d_in, const int* in_sizes, int n_in,
                              void* d_out, int out_size, void* d_ws, size_t ws_size,
                              hipStream_t stream) {
    const float* x      = (const float*)d_in[0];
    const float* n1w    = (const float*)d_in[1];
    const float* n1b    = (const float*)d_in[2];
    const float* w_qkv  = (const float*)d_in[3];
    const float* w_dw   = (const float*)d_in[4];
    const float* temp   = (const float*)d_in[5];
    const float* w_proj = (const float*)d_in[6];
    const float* b_proj = (const float*)d_in[7];
    const float* n2w    = (const float*)d_in[8];
    const float* n2b    = (const float*)d_in[9];
    const float* w_in   = (const float*)d_in[10];
    const float* w_dwf  = (const float*)d_in[11];
    const float* w_out  = (const float*)d_in[12];
    float* outp = (float*)d_out;

    // workspace: 236,961,792 bytes
    const long CS = (long)Cc * S;
    const size_t DCT_B = 147456;
    const size_t BUF_B = (size_t)Bn * CS * 2;
    const size_t QKV_B = (size_t)Bn * 3 * CS * 2;
    const size_t WB_B  = 884736;
    const size_t GT_B  = (size_t)Bn * GTR2 * 512 * 2;
    const size_t NEED  = DCT_B + 4 * BUF_B + QKV_B + WB_B + GT_B;
    if (ws_size < NEED) return;

    char* p = (char*)d_ws;
    bft* dctb  = (bft*)p;
    bft* dctTb = dctb + L * L;
    p += DCT_B;
    bft* X1    = (bft*)p;                  p += BUF_B;
    bft* PbB   = (bft*)p;                  p += BUF_B;
    bft* QbB   = (bft*)p;                  p += BUF_B;
    bft* VW    = (bft*)p;                  p += BUF_B;   // v-dwconv output
    bft* QKV   = (bft*)p;                  p += QKV_B;
    bft* w_qkv_b = (bft*)p;
    bft* w_proj_b = w_qkv_b + 576 * 192;
    bft* w_in_b  = w_proj_b + 192 * 192;
    bft* w_out_b = w_in_b + 1024 * 192;
    p += WB_B;
    bft* gT = (bft*)p;                     // [2][GTR2][512]
    bft* fT = QKV;                         // [2][FTR2][1024] (reuses QKV)
    bft* attnT = QKV + CS;

    k_dct_init<<<144, BLK, 0, stream>>>(dctb, dctTb);
    k_cvt<<<432, BLK, 0, stream>>>(w_qkv, w_qkv_b, 576, 192, 192);
    k_cvt<<<144, BLK, 0, stream>>>(w_proj, w_proj_b, 192, 192, 192);
    k_cvt_ffn<<<768, BLK, 0, stream>>>(w_in, w_in_b);
    k_cvt<<<384, BLK, 0, stream>>>(w_out, w_out_b, 192, 510, 512);

    // ---------------- attention branch (both batches per dispatch) -----------
    k_lnt<float, false><<<dim3(S / 64, Bn), BLK, 0, stream>>>(x, n1w, n1b, PbB, CS, CS);
    k_mm<2, 2, 2, 6, 32, 2, 3, false, false, false, false, false, false, bft, float><<<dim3(1, 3, Bn * Cc), 256, 0, stream>>>(
        PbB, L, L, S,  dctb, L, 0,  QbB, L, S,  nullptr, nullptr, 0,  L, 0, 0);
    k_mm<2, 2, 2, 6, 32, 2, 3, false, false, false, false, false, false, bft, float><<<dim3(1, 3, Bn * Cc), 256, 0, stream>>>(
        QbB, L, L, S,  dctb, L, 0,  PbB, L, S,  nullptr, nullptr, 0,  L, 0, 0);
    k_tr<<<dim3(576, 6, Bn), BLK, 0, stream>>>(PbB, QbB, CS);
    // qkv: A=w_qkv (L2), B=ydT rows; GSWAP+SWIZ keeps B slice on one XCD
    k_mm<2, 2, 4, 4, 32, 2, 5, true, true, false, false, false, false, bft, float><<<dim3(5, 288, Bn), 256, 0, stream>>>(
        w_qkv_b, Cc, 576, 0,  QbB, Cc, CS,  QKV, S, 3 * CS,  nullptr, nullptr, 0,  Cc, 0, 0);
    // fused depthwise, window-row aligned (q->PbB, k->QbB, v->VW)
    k_dwconv3b<<<dim3(Bn * 576, 24), BLK, 0, stream>>>(QKV, w_dw, PbB, QbB, VW, CS);
    k_attn_mfma<<<dim3(144, 6, Bn), 256, 0, stream>>>(
        PbB, CS, QbB, CS, VW, CS, temp, attnT, 3 * CS);
    // projT[s*][c] = attnT . w_proj^T + b ; OMODE5 -> full-line row writes
    k_mm<2, 2, 2, 6, 32, 2, 5, false, false, false, true, true, false, bft, float><<<dim3(1, 576, Bn), 256, 0, stream>>>(
        attnT, Cc, S, 3 * CS,  w_proj_b, Cc, 0,  PbB, Cc, CS,  b_proj, (const float*)nullptr, 0,  Cc, 0, 0);
    k_w2s<<<dim3(192, 2, Bn), BLK, 0, stream>>>(PbB, QbB, CS, CS);
    k_mm<2, 2, 2, 6, 32, 2, 3, false, false, false, false, false, false, bft, float><<<dim3(1, 3, Bn * Cc), 256, 0, stream>>>(
        QbB, L, L, S,  dctTb, L, 0,  PbB, L, S,  nullptr, nullptr, 0,  L, 0, 0);
    // G4: OMODE5 + fp32 residual (row-contiguous) -> X1
    k_mm<2, 2, 2, 6, 32, 2, 5, false, false, false, false, false, true, bft, float><<<dim3(1, 3, Bn * Cc), 256, 0, stream>>>(
        dctTb, L, L, 0,  PbB, L, S,  X1, L, S,  nullptr, x, S,  L, 0, 0);

    // ---------------- FFN branch (2 chunks of 96 rows) -----------------------
    k_lnt<bft, true><<<dim3(S / 64, Bn), BLK, 0, stream>>>(X1, n2w, n2b, QbB, CS, CS);
    for (int ck = 0; ck < 2; ++ck) {
        int h0 = ck * CH2;
        long off = (long)(h0 - 1) * L;
        int rlo = (ck == 0) ? L : 0;
        int rhi = (ck == 1) ? (FTR2 - L) : FTR2;
        // fT: A=w_in, B=zT masked rows; GSWAP+SWIZ
        k_mm<2, 2, 4, 4, 32, 4, 3, true, true, false, false, false, false, bft, float><<<dim3(8, 147, Bn), 256, 0, stream>>>(
            w_in_b, Cc, 1024, 0,  QbB + off * Cc, Cc, CS,  fT, 1024, (long)FTR2 * 1024,
            nullptr, nullptr, 0,  Cc, rlo, rhi);
        k_gateT<<<dim3(GTR2 / 32, 8, Bn), BLK, 0, stream>>>(fT, w_dwf, gT);
        // wout: A=w_out, B=gT rows; GSWAP+SWIZ, fp32 64B-run stores
        k_mm<2, 2, 2, 4, 32, 2, 0, true, true, false, false, false, true, float, bft><<<dim3(3, 144, Bn), 256, 0, stream>>>(
            w_out_b, 512, 192, 0,  gT, 512, (long)GTR2 * 512,
            outp + (size_t)ck * GTR2, S, CS,
            nullptr, X1 + (size_t)ck * GTR2, CS,  512, 0, 0);
    }
}